// Round 8
// baseline (188.247 us; speedup 1.0000x reference)
//
#include <hip/hip_runtime.h>
#include <hip/hip_bf16.h>

// Problem sizes (fixed): B=16, N_LOG=512, N_PHYS(Q)=2048, E=2048
#define BATCH 16
#define NLOG 512
#define Q 2048
#define NEDGE 2048
#define KTOT 8192              // gemm2 K = BATCH*NLOG

typedef float f32x4 __attribute__((ext_vector_type(4)));
typedef int i32x4 __attribute__((ext_vector_type(4)));
typedef int i32x8 __attribute__((ext_vector_type(8)));

__device__ __forceinline__ unsigned char to_e4m3(float f) {
    int pk = __builtin_amdgcn_cvt_pk_fp8_f32(f, f, 0, false);
    return (unsigned char)(pk & 0xff);
}

// ---------------------------------------------------------------------------
// K1 prep (grid 16384+512+16):
//  blocks [0,16384): P[b,i,p] fp32 -> P8t[p][b*512+i] e4m3 via 32x32 LDS
//                    transpose (1024 tiles/batch).
//  blocks [16384,16896): build bitmask mask[p][qw] bit q%32 = (d_hw[p][q]==1).
//  blocks [16896,16912): sw[b] = sum_e ew; block 0 zeroes total+counter.
__global__ __launch_bounds__(256) void prep(const float* __restrict__ P,
                                            unsigned char* __restrict__ P8t,
                                            const int* __restrict__ d_hw,
                                            unsigned* __restrict__ mask,
                                            const float* __restrict__ ew,
                                            float* __restrict__ sw,
                                            float* __restrict__ total,
                                            unsigned* __restrict__ counter) {
    const int t = threadIdx.x;
    int bid = blockIdx.x;
    if (bid < 16384) {
        __shared__ unsigned char tile[32][36];
        const int b = bid >> 10;
        const int tb = bid & 1023;
        const int i0 = (tb >> 6) * 32;    // i-tile
        const int p0 = (tb & 63) * 32;    // p-tile
        const int tx = t & 31, ty = t >> 5;
        #pragma unroll
        for (int s = 0; s < 4; s++) {
            int r = ty + s * 8;
            float v = P[(size_t)(b * NLOG + i0 + r) * Q + p0 + tx];
            tile[r][tx] = to_e4m3(v);
        }
        __syncthreads();
        // out row p0+r2 (len 8192), cols b*512+i0+c4.. (4B per thread)
        const int r2 = t >> 3;
        const int c4 = (t & 7) * 4;
        uchar4 o;
        o.x = tile[c4 + 0][r2];
        o.y = tile[c4 + 1][r2];
        o.z = tile[c4 + 2][r2];
        o.w = tile[c4 + 3][r2];
        *(uchar4*)(P8t + (size_t)(p0 + r2) * KTOT + b * NLOG + i0 + c4) = o;
    } else if (bid < 16896) {
        int wordid = (bid - 16384) * 256 + t;     // [0, 131072)
        int p = wordid >> 6;
        int qw = wordid & 63;
        unsigned m = 0;
        #pragma unroll
        for (int u = 0; u < 32; u++) {
            int d = d_hw[(size_t)p * Q + qw * 32 + u];
            m |= (unsigned)(d == 1) << u;
        }
        mask[wordid] = m;
    } else {
        int b = bid - 16896;
        if (b == 0 && t == 0) { *total = 0.f; *counter = 0u; }
        float s = 0.f;
        #pragma unroll
        for (int k = 0; k < 8; k++) s += ew[b * NEDGE + k * 256 + t];
        #pragma unroll
        for (int off = 32; off > 0; off >>= 1) s += __shfl_xor(s, off);
        __shared__ float red[4];
        if ((t & 63) == 0) red[t >> 6] = s;
        __syncthreads();
        if (t == 0) sw[b] = red[0] + red[1] + red[2] + red[3];
    }
}

// ---------------------------------------------------------------------------
// K2: scatter W_b[src,dst] += w  (fp32, atomic; Wf32 pre-zeroed by memset).
__global__ __launch_bounds__(256) void scatter_w(const int* __restrict__ esrc,
                                                 const int* __restrict__ edst,
                                                 const float* __restrict__ ew,
                                                 float* __restrict__ Wf32) {
    const int b = blockIdx.x;
    const int t = threadIdx.x;
    #pragma unroll
    for (int s = 0; s < 8; s++) {
        int e = b * NEDGE + s * 256 + t;
        atomicAdd(&Wf32[(size_t)b * NLOG * NLOG + esrc[e] * NLOG + edst[e]], ew[e]);
    }
}

// ---------------------------------------------------------------------------
// K3: convert Wf32 -> W8 (e4m3). 4.19M elements.
__global__ __launch_bounds__(256) void cvt_w(const float* __restrict__ Wf32,
                                             unsigned char* __restrict__ W8) {
    int i = (blockIdx.x * 256 + threadIdx.x) * 4;
    float4 v = *(const float4*)(Wf32 + i);
    int pk = 0;
    pk = __builtin_amdgcn_cvt_pk_fp8_f32(v.x, v.y, pk, false);
    pk = __builtin_amdgcn_cvt_pk_fp8_f32(v.z, v.w, pk, true);
    *(int*)(W8 + i) = pk;
}

// ---------------------------------------------------------------------------
// K4: gemm1  Vt[q, b*512+i] = (1024/sw_b) * sum_j P8t[q, b*512+j] * W8_b[i,j]
// 256(q) x 128(i) tile, K=512 (4 iters BK=128). Same proven staging/swizzle/
// MFMA structure as R7's gemm_bt8. Epilogue: scale -> e4m3 -> LDS bounce ->
// coalesced 16B stores into Vt rows.
__global__ __launch_bounds__(256, 2) void gemm1(const unsigned char* __restrict__ P8t,
                                                const unsigned char* __restrict__ W8,
                                                const float* __restrict__ sw,
                                                unsigned char* __restrict__ Vt) {
    __shared__ unsigned char As[32768];  // 256 x 128
    __shared__ unsigned char Bs[16384];  // 128 x 128

    const int t = threadIdx.x;
    const int w = t >> 6;
    const int wr = w >> 1, wc = w & 1;
    const int l = t & 63;
    const int quad = l >> 4;
    const int lane16 = l & 15;

    const int b = blockIdx.z;
    const int m0 = blockIdx.x * 256;     // q
    const int n0 = blockIdx.y * 128;     // i

    const int s_row = t >> 3;
    const int s_off = (((t & 7) ^ (s_row & 7)) << 4);
    const int r7 = lane16 & 7;
    const int c0 = ((2 * quad) ^ r7) << 4;
    const int c1 = ((2 * quad + 1) ^ r7) << 4;

    const unsigned char* Wb = W8 + (size_t)b * NLOG * NLOG;

    f32x4 acc[8][4] = {};

    for (int k0 = 0; k0 < NLOG; k0 += 128) {
        #pragma unroll
        for (int c = 0; c < 8; c++) {
            const unsigned char* g = P8t + (size_t)(m0 + c * 32 + s_row) * KTOT
                                     + b * NLOG + k0 + s_off;
            __builtin_amdgcn_global_load_lds(
                (const __attribute__((address_space(1))) void*)g,
                (__attribute__((address_space(3))) void*)(As + c * 4096 + w * 1024),
                16, 0, 0);
        }
        #pragma unroll
        for (int c = 0; c < 4; c++) {
            const unsigned char* g = Wb + (size_t)(n0 + c * 32 + s_row) * NLOG
                                     + k0 + s_off;
            __builtin_amdgcn_global_load_lds(
                (const __attribute__((address_space(1))) void*)g,
                (__attribute__((address_space(3))) void*)(Bs + c * 4096 + w * 1024),
                16, 0, 0);
        }
        __syncthreads();

        i32x8 bfr[4];
        #pragma unroll
        for (int j = 0; j < 4; j++) {
            int base = (wc * 64 + j * 16 + lane16) << 7;
            i32x4 lo = *(const i32x4*)(Bs + base + c0);
            i32x4 hi = *(const i32x4*)(Bs + base + c1);
            bfr[j] = __builtin_shufflevector(lo, hi, 0, 1, 2, 3, 4, 5, 6, 7);
        }
        #pragma unroll
        for (int i = 0; i < 8; i++) {
            int base = (wr * 128 + i * 16 + lane16) << 7;
            i32x4 lo = *(const i32x4*)(As + base + c0);
            i32x4 hi = *(const i32x4*)(As + base + c1);
            i32x8 af = __builtin_shufflevector(lo, hi, 0, 1, 2, 3, 4, 5, 6, 7);
            #pragma unroll
            for (int j = 0; j < 4; j++)
                acc[i][j] = __builtin_amdgcn_mfma_scale_f32_16x16x128_f8f6f4(
                    af, bfr[j], acc[i][j], 0, 0, 0, 127, 0, 127);
        }
        __syncthreads();
    }

    // epilogue: scale, quantize, LDS-bounce for coalesced stores
    const float scale = 1024.0f / fmaxf(sw[b], 1e-8f);
    unsigned char* Cs = As;              // reuse (post-barrier, all reads done)
    #pragma unroll
    for (int i = 0; i < 8; i++)
        #pragma unroll
        for (int j = 0; j < 4; j++)
            #pragma unroll
            for (int r = 0; r < 4; r++) {
                int row = wr * 128 + i * 16 + quad * 4 + r;
                int col = wc * 64 + j * 16 + lane16;
                Cs[row * 128 + col] = to_e4m3(acc[i][j][r] * scale);
            }
    __syncthreads();
    #pragma unroll
    for (int s = 0; s < 8; s++) {
        int idx = s * 4096 + t * 16;
        int row = idx >> 7;
        int col = idx & 127;
        *(i32x4*)(Vt + (size_t)(m0 + row) * KTOT + b * NLOG + n0 + col) =
            *(const i32x4*)(Cs + idx);
    }
}

// ---------------------------------------------------------------------------
// K5: gemm2 + fused mask-reduce.
//   partial = sum_{p,q in tile} mask[p,q] * sum_k P8t[p,k]*Vt[q,k]
// 256(p) x 128(q) tile, split-K x4 (K-chunk 2048, 16 iters). Grid (8,16,4)
// = 512 blocks, 2/CU. No output tensor: one atomicAdd(total) per block;
// last block (done-counter) writes the loss.
__global__ __launch_bounds__(256, 2) void gemm2(const unsigned char* __restrict__ P8t,
                                                const unsigned char* __restrict__ Vt,
                                                const unsigned* __restrict__ mask,
                                                float* __restrict__ total,
                                                unsigned* __restrict__ counter,
                                                float* __restrict__ out) {
    __shared__ unsigned char As[32768];  // 256 x 128
    __shared__ unsigned char Bs[16384];  // 128 x 128

    const int t = threadIdx.x;
    const int w = t >> 6;
    const int wr = w >> 1, wc = w & 1;
    const int l = t & 63;
    const int quad = l >> 4;
    const int lane16 = l & 15;

    const int m0 = blockIdx.x * 256;     // p
    const int n0 = blockIdx.y * 128;     // q
    const int kbase = blockIdx.z * 2048; // split-K chunk

    const int s_row = t >> 3;
    const int s_off = (((t & 7) ^ (s_row & 7)) << 4);
    const int r7 = lane16 & 7;
    const int c0 = ((2 * quad) ^ r7) << 4;
    const int c1 = ((2 * quad + 1) ^ r7) << 4;

    f32x4 acc[8][4] = {};

    for (int k0 = 0; k0 < 2048; k0 += 128) {
        #pragma unroll
        for (int c = 0; c < 8; c++) {
            const unsigned char* g = P8t + (size_t)(m0 + c * 32 + s_row) * KTOT
                                     + kbase + k0 + s_off;
            __builtin_amdgcn_global_load_lds(
                (const __attribute__((address_space(1))) void*)g,
                (__attribute__((address_space(3))) void*)(As + c * 4096 + w * 1024),
                16, 0, 0);
        }
        #pragma unroll
        for (int c = 0; c < 4; c++) {
            const unsigned char* g = Vt + (size_t)(n0 + c * 32 + s_row) * KTOT
                                     + kbase + k0 + s_off;
            __builtin_amdgcn_global_load_lds(
                (const __attribute__((address_space(1))) void*)g,
                (__attribute__((address_space(3))) void*)(Bs + c * 4096 + w * 1024),
                16, 0, 0);
        }
        __syncthreads();

        i32x8 bfr[4];
        #pragma unroll
        for (int j = 0; j < 4; j++) {
            int base = (wc * 64 + j * 16 + lane16) << 7;
            i32x4 lo = *(const i32x4*)(Bs + base + c0);
            i32x4 hi = *(const i32x4*)(Bs + base + c1);
            bfr[j] = __builtin_shufflevector(lo, hi, 0, 1, 2, 3, 4, 5, 6, 7);
        }
        #pragma unroll
        for (int i = 0; i < 8; i++) {
            int base = (wr * 128 + i * 16 + lane16) << 7;
            i32x4 lo = *(const i32x4*)(As + base + c0);
            i32x4 hi = *(const i32x4*)(As + base + c1);
            i32x8 af = __builtin_shufflevector(lo, hi, 0, 1, 2, 3, 4, 5, 6, 7);
            #pragma unroll
            for (int j = 0; j < 4; j++)
                acc[i][j] = __builtin_amdgcn_mfma_scale_f32_16x16x128_f8f6f4(
                    af, bfr[j], acc[i][j], 0, 0, 0, 127, 0, 127);
        }
        __syncthreads();
    }

    // fused mask-dot epilogue
    float part = 0.f;
    #pragma unroll
    for (int i = 0; i < 8; i++) {
        #pragma unroll
        for (int r = 0; r < 4; r++) {
            int p = m0 + wr * 128 + i * 16 + quad * 4 + r;
            #pragma unroll
            for (int j = 0; j < 4; j++) {
                int q = n0 + wc * 64 + j * 16 + lane16;
                unsigned mw = mask[p * (Q / 32) + (q >> 5)];
                if ((mw >> (q & 31)) & 1u) part += acc[i][j][r];
            }
        }
    }
    #pragma unroll
    for (int off = 32; off > 0; off >>= 1) part += __shfl_xor(part, off);
    __shared__ float red[4];
    if (l == 0) red[w] = part;
    __syncthreads();

    __shared__ unsigned done;
    if (t == 0) {
        atomicAdd(total, red[0] + red[1] + red[2] + red[3]);
        __threadfence();
        done = atomicAdd(counter, 1u);
    }
    __syncthreads();
    if (t == 0 && done == 8 * 16 * 4 - 1) {
        __threadfence();
        float tv = atomicAdd(total, 0.0f);   // device-scope read
        out[0] = -tv / 16384.0f;             // /(1024 * BATCH)
    }
}

// ---------------------------------------------------------------------------
extern "C" void kernel_launch(void* const* d_in, const int* in_sizes, int n_in,
                              void* d_out, int out_size, void* d_ws, size_t ws_size,
                              hipStream_t stream) {
    const float* P    = (const float*)d_in[0];
    const int* d_hw   = (const int*)d_in[1];
    const int* esrc   = (const int*)d_in[2];
    const int* edst   = (const int*)d_in[3];
    const float* ew   = (const float*)d_in[4];
    float* out        = (float*)d_out;

    char* ws = (char*)d_ws;
    // workspace layout (bytes), total ~38.3 MB:
    //   P8t  : e4m3 [Q][B*N]    = 16,777,216   [0, 16.8M)
    //   W8   : e4m3 [B][N][N]   =  4,194,304   [16.8M, 21.0M)
    //   Wf32 : f32  [B][N][N]   = 16,777,216   [21.0M, 37.7M)  dead after cvt_w
    //   Vt   : e4m3 [Q][B*N]    = 16,777,216   ALIASES Wf32
    //   mask : u32  [Q][64]     =    524,288   [37.7M, 38.3M)
    //   sw/total/counter at 38.3M
    unsigned char* P8t = (unsigned char*)ws;
    unsigned char* W8  = (unsigned char*)(ws + 16777216);
    float* Wf32        = (float*)(ws + 20971520);
    unsigned char* Vt  = (unsigned char*)(ws + 20971520);  // alias (after cvt_w)
    unsigned* mask     = (unsigned*)(ws + 37748736);
    float* sw          = (float*)(ws + 38273024);
    float* total       = (float*)(ws + 38273088);
    unsigned* counter  = (unsigned*)(ws + 38273152);

    hipMemsetAsync(Wf32, 0, 16777216, stream);
    prep<<<16384 + 512 + 16, 256, 0, stream>>>(P, P8t, d_hw, mask, ew, sw,
                                               total, counter);
    scatter_w<<<BATCH, 256, 0, stream>>>(esrc, edst, ew, Wf32);
    cvt_w<<<4096, 256, 0, stream>>>(Wf32, W8);
    gemm1<<<dim3(Q / 256, NLOG / 128, BATCH), 256, 0, stream>>>(P8t, W8, sw, Vt);
    gemm2<<<dim3(Q / 256, Q / 128, 4), 256, 0, stream>>>(P8t, Vt, mask, total,
                                                         counter, out);
}